// Round 6
// baseline (48.473 us; speedup 1.0000x reference)
//
#include <hip/hip_runtime.h>
#include <stdint.h>
#include <math.h>

#define NBOX 18
#define BB 512
#define DD 2048
#define NOBJ 16
#define KK 3
#define NCLS 174
#define NCAT 321
#define NQ 4
#define QCAND 2048
#define NPART 16  /* per-wave partials per b: NQ blocks x 4 waves */
#define TINYF 1.1754943508222875e-38f

// ---------------- threefry2x32 (JAX-exact, 20 rounds) ----------------
__host__ __device__ __forceinline__ uint32_t rotl32(uint32_t x, int d) {
  return (x << d) | (x >> (32 - d));
}

__host__ __device__ __forceinline__ void threefry2x32(uint32_t k0, uint32_t k1,
                                                      uint32_t x0, uint32_t x1,
                                                      uint32_t& o0, uint32_t& o1) {
  uint32_t ks2 = k0 ^ k1 ^ 0x1BD11BDAu;
  x0 += k0; x1 += k1;
#define TFR(r) x0 += x1; x1 = rotl32(x1, r); x1 ^= x0;
#define R4A TFR(13) TFR(15) TFR(26) TFR(6)
#define R4B TFR(17) TFR(29) TFR(16) TFR(24)
  R4A x0 += k1;  x1 += ks2 + 1u;
  R4B x0 += ks2; x1 += k0 + 2u;
  R4A x0 += k0;  x1 += k1 + 3u;
  R4B x0 += k1;  x1 += ks2 + 4u;
  R4A x0 += ks2; x1 += k0 + 5u;
#undef R4A
#undef R4B
#undef TFR
  o0 = x0; o1 = x1;
}

__device__ __forceinline__ float bits_to_unit(uint32_t bits) {
  float f = __uint_as_float((bits >> 9) | 0x3f800000u);
  return f - 1.0f;
}

// ---- Kernel A: sampler quarter + overlapped ori/S16 stream ----
// grid 2048 = (b, quarter q); 256 threads = 4 waves. NO __syncthreads until
// consume (a barrier would drain vmcnt and kill the stream overlap).
__global__ __launch_bounds__(256) void fused_sample_ori(
    const float* __restrict__ obj_fea, const float* __restrict__ cooc,
    const int* __restrict__ obj_cat, const int* __restrict__ labels,
    uint32_t r1h, uint32_t r1l,
    unsigned long long* __restrict__ part, int* __restrict__ cnts,
    float* __restrict__ ori, float4* __restrict__ s16ws) {
  const int gb = blockIdx.x;
  const int b = gb >> 2;
  const int q = gb & 3;
  const int tid = threadIdx.x;
  const int lane = tid & 63;
  const int wid = tid >> 6;

  __shared__ unsigned short jl[QCAND];   // 4 KB, per-wave 512-stripes
  __shared__ float wl[QCAND];            // 8 KB
  __shared__ float scrow[4 * 336];       // 5.25 KB wave-private cooc rows
  __shared__ float4 xch[128];            // 2 KB half-combine buffer

  // ---- p0 (FIRST): 9 named float4 loads per thread; land during p1+p2
  const int col = tid & 127;
  const int half = tid >> 7;
  const float4* fea4 = (const float4*)obj_fea;
  const size_t lbase = ((size_t)b * NBOX + half * 9) * 512 + (q << 7) + col;
  float4 a0 = fea4[lbase];
  float4 a1 = fea4[lbase + 512];
  float4 a2 = fea4[lbase + 2 * 512];
  float4 a3 = fea4[lbase + 3 * 512];
  float4 a4 = fea4[lbase + 4 * 512];
  float4 a5 = fea4[lbase + 5 * 512];
  float4 a6 = fea4[lbase + 6 * 512];
  float4 a7 = fea4[lbase + 7 * 512];
  float4 a8 = fea4[lbase + 8 * 512];
  __builtin_amdgcn_sched_barrier(0);  // pin the stream issue above everything

  // ---- p1a: wave-private staging of this label's cooc row (no barrier)
  const int lab = labels[b];
  const float* crow = cooc + (size_t)lab * NCAT;
  const int cbase_lds = wid * 336;
  for (int i = lane; i < NCAT; i += 64) scrow[cbase_lds + i] = crow[i];

  // ---- p1b: per-wave ordered compaction (ballot+popcount, j-ascending)
  const int seg = wid << 9;
  const int jbase = (q << 11) + seg;
  int cnt = 0;
#pragma unroll 1
  for (int c = 0; c < 8; ++c) {
    int j = jbase + (c << 6) + lane;
    int jb = j >> 4;
    float w = 0.0f;
    if (jb != b) w = scrow[cbase_lds + obj_cat[jb * NBOX + 2 + (j & 15)]];
    unsigned long long m = __ballot(w > 0.0f);
    if (w > 0.0f) {
      int rank = __popcll(m & ((1ull << lane) - 1ull));
      jl[seg + cnt + rank] = (unsigned short)j;
      wl[seg + cnt + rank] = w;
    }
    cnt += __popcll(m);
  }

  // ---- p2: 3-in-1 exponential races: argmax(g + log w) == argmax(w / -log u)
  const uint32_t cbase0 = ((uint32_t)b) << 13;  // k stride = 512*8192 = 1<<22
  const uint32_t kstep = 1u << 22;
  float br0 = 0.f, br1 = 0.f, br2 = 0.f;
  int bj0 = 0, bj1 = 0, bj2 = 0;
#pragma unroll 1
  for (int p = lane; p < cnt; p += 64) {
    uint32_t j = jl[seg + p];
    float w = wl[seg + p];
    uint32_t cc = cbase0 + j;
    uint32_t x0, x1, y0, y1, z0, z1;
    threefry2x32(r1h, r1l, 0u, cc, x0, x1);
    threefry2x32(r1h, r1l, 0u, cc + kstep, y0, y1);
    threefry2x32(r1h, r1l, 0u, cc + 2u * kstep, z0, z1);
    float t0 = -logf(fmaxf(bits_to_unit(x0 ^ x1), TINYF));
    float t1 = -logf(fmaxf(bits_to_unit(y0 ^ y1), TINYF));
    float t2 = -logf(fmaxf(bits_to_unit(z0 ^ z1), TINYF));
    if (w > br0 * t0) { br0 = w / t0; bj0 = (int)j; }  // strict >: first idx kept
    if (w > br1 * t1) { br1 = w / t1; bj1 = (int)j; }
    if (w > br2 * t2) { br2 = w / t2; bj2 = (int)j; }
  }
#pragma unroll
  for (int mm = 1; mm < 64; mm <<= 1) {
    float ov; int oj;
    ov = __shfl_xor(br0, mm, 64); oj = __shfl_xor(bj0, mm, 64);
    if (ov > br0 || (ov == br0 && oj < bj0)) { br0 = ov; bj0 = oj; }
    ov = __shfl_xor(br1, mm, 64); oj = __shfl_xor(bj1, mm, 64);
    if (ov > br1 || (ov == br1 && oj < bj1)) { br1 = ov; bj1 = oj; }
    ov = __shfl_xor(br2, mm, 64); oj = __shfl_xor(bj2, mm, 64);
    if (ov > br2 || (ov == br2 && oj < bj2)) { br2 = ov; bj2 = oj; }
  }
  if (lane == 0) {
    // per-wave packed partial: high=ratio bits (>=0, monotone), low=8192-j
    const int pw = q * 4 + wid;
    const size_t pb = (size_t)b * KK * NPART;
    part[pb + 0 * NPART + pw] =
        ((unsigned long long)__float_as_uint(br0) << 32) | (uint32_t)(8192 - bj0);
    part[pb + 1 * NPART + pw] =
        ((unsigned long long)__float_as_uint(br1) << 32) | (uint32_t)(8192 - bj1);
    part[pb + 2 * NPART + pw] =
        ((unsigned long long)__float_as_uint(br2) << 32) | (uint32_t)(8192 - bj2);
    cnts[b * NPART + pw] = cnt;
  }

  // ---- p3: consume the stream, combine halves, write ori + S16
  float4 A;
  A.x = a0.x + a1.x + a2.x + a3.x + a4.x + a5.x + a6.x + a7.x + a8.x;
  A.y = a0.y + a1.y + a2.y + a3.y + a4.y + a5.y + a6.y + a7.y + a8.y;
  A.z = a0.z + a1.z + a2.z + a3.z + a4.z + a5.z + a6.z + a7.z + a8.z;
  A.w = a0.w + a1.w + a2.w + a3.w + a4.w + a5.w + a6.w + a7.w + a8.w;
  if (half) xch[col] = A;  // sum rows 9..17
  __syncthreads();
  if (!half) {
    float4 Bv = xch[col];
    float4 S = make_float4(A.x + Bv.x, A.y + Bv.y, A.z + Bv.z, A.w + Bv.w);
    const float is = 1.0f / 18.0f;
    const size_t oidx = (size_t)b * 512 + (q << 7) + col;
    ((float4*)ori)[oidx] = make_float4(S.x * is, S.y * is, S.z * is, S.w * is);
    s16ws[oidx] = make_float4(S.x - a0.x - a1.x, S.y - a0.y - a1.y,
                              S.z - a0.z - a1.z, S.w - a0.w - a1.w);
  }
}

// ---- Kernel B: mix finisher ----
__global__ __launch_bounds__(256) void mix_kernel(
    const float* __restrict__ obj_fea, const int* __restrict__ obj_ind,
    const int* __restrict__ labels,
    const unsigned long long* __restrict__ part, const int* __restrict__ cnts,
    const float4* __restrict__ s16ws,
    uint32_t r2h, uint32_t r2l, uint32_t r3bh, uint32_t r3bl,
    float* __restrict__ mixf, float* __restrict__ mixl) {
  const int bx = blockIdx.x;
  const int b = bx >> 1;
  const int h = bx & 1;
  const int tid = threadIdx.x;
  const int off = (h << 8) + tid;

  __shared__ int s_sel[KK];
  __shared__ int s_slots[KK];
  __shared__ float s_lam;
  __shared__ int s_hc;
  if (tid < KK) {
    const int k = tid;
    const unsigned long long* pp = part + ((size_t)b * KK + k) * NPART;
    unsigned long long best = pp[0];
#pragma unroll
    for (int p = 1; p < NPART; ++p) {
      unsigned long long v = pp[p];
      if (v > best) best = v;
    }
    s_sel[k] = 8192 - (int)(best & 0xFFFFFFFFull);
    uint32_t s0, s1;
    threefry2x32(r3bh, r3bl, 0u, (uint32_t)(b * KK + k), s0, s1);
    s_slots[k] = (int)((s0 ^ s1) & 15u);
  } else if (tid == 3) {
    int tot = 0;
#pragma unroll
    for (int p = 0; p < NPART; ++p) tot += cnts[b * NPART + p];
    int any = 0;
#pragma unroll
    for (int o = 0; o < NOBJ; ++o) any |= (obj_ind[b * NBOX + 2 + o] != 0);
    s_hc = (tot > 0) && any;
  } else if (tid == 4) {
    uint32_t c0, c1;
    threefry2x32(r2h, r2l, 0u, (uint32_t)b, c0, c1);
    s_lam = bits_to_unit(c0 ^ c1);
  }
  __syncthreads();

  const int hc = s_hc;
  const float l = s_lam, l1 = 1.0f - l;
  const float4* fea4 = (const float4*)obj_fea;
  float4* mixf4 = (float4*)mixf;
  if (hc) {
#pragma unroll 1
    for (int k = 0; k < KK; ++k) {
      int s = s_sel[k];
      int bi = s >> 4, bo = s & 15, sl = s_slots[k];
      float4 a = fea4[((size_t)b * NBOX + 2 + sl) * 512 + off];
      float4 e = fea4[((size_t)bi * NBOX + 2 + bo) * 512 + off];
      float4 o;
      o.x = a.x * l + e.x * l1; o.y = a.y * l + e.y * l1;
      o.z = a.z * l + e.z * l1; o.w = a.w * l + e.w * l1;
      mixf4[((size_t)b * KK + k) * 512 + off] = o;
    }
  } else {
    float4 s16 = s16ws[(size_t)b * 512 + off];
    const float is = 1.0f / 16.0f;
    float4 o = make_float4(s16.x * is, s16.y * is, s16.z * is, s16.w * is);
#pragma unroll
    for (int k = 0; k < KK; ++k) mixf4[((size_t)b * KK + k) * 512 + off] = o;
  }

  if (h == 0 && tid < NCLS) {
    int lb = labels[b];
#pragma unroll 1
    for (int k = 0; k < KK; ++k) {
      float val;
      if (hc) {
        int ls = labels[s_sel[k] >> 4];
        val = (tid == lb ? l : 0.0f) + (tid == ls ? l1 : 0.0f);
      } else {
        val = (tid == lb) ? 1.0f : 0.0f;
      }
      mixl[(size_t)(b * KK + k) * NCLS + tid] = val;
    }
  }
}

extern "C" void kernel_launch(void* const* d_in, const int* in_sizes, int n_in,
                              void* d_out, int out_size, void* d_ws, size_t ws_size,
                              hipStream_t stream) {
  (void)in_sizes; (void)n_in; (void)out_size; (void)ws_size;
  const float* obj_fea = (const float*)d_in[0];
  const float* cooc    = (const float*)d_in[1];
  const int* obj_ind   = (const int*)d_in[2];
  const int* obj_cat   = (const int*)d_in[3];
  const int* labels    = (const int*)d_in[4];

  float* out  = (float*)d_out;
  float* ori  = out;                              // 512*2048
  float* mixf = out + (size_t)BB * DD;            // 512*3*2048
  float* mixl = mixf + (size_t)BB * KK * DD;      // 512*3*174

  char* ws = (char*)d_ws;
  unsigned long long* part = (unsigned long long*)ws;      // 512*3*16*8 = 192 KB
  int* cnts = (int*)(ws + (size_t)BB * KK * NPART * 8);    // 512*16*4 = 32 KB
  float4* s16ws = (float4*)(ws + 256 * 1024);              // 4 MB

  // key(42) -> split 3 (partitionable/fold-like): r_i = threefry(key,(0,i))
  uint32_t r1h, r1l, r2h, r2l, r3h, r3l;
  threefry2x32(0u, 42u, 0u, 0u, r1h, r1l);
  threefry2x32(0u, 42u, 0u, 1u, r2h, r2l);
  threefry2x32(0u, 42u, 0u, 2u, r3h, r3l);
  // randint(r3,...) splits internally: k1,k2 = split(r3); lower_bits uses k2
  uint32_t r3bh, r3bl;
  threefry2x32(r3h, r3l, 0u, 1u, r3bh, r3bl);

  hipLaunchKernelGGL(fused_sample_ori, dim3(BB * NQ), dim3(256), 0, stream,
                     obj_fea, cooc, obj_cat, labels, r1h, r1l,
                     part, cnts, ori, s16ws);
  hipLaunchKernelGGL(mix_kernel, dim3(BB * 2), dim3(256), 0, stream,
                     obj_fea, obj_ind, labels, part, cnts, s16ws,
                     r2h, r2l, r3bh, r3bl, mixf, mixl);
}

// Round 7
// 46.413 us; speedup vs baseline: 1.0444x; 1.0444x over previous
//
#include <hip/hip_runtime.h>
#include <stdint.h>
#include <math.h>

#define NBOX 18
#define BB 512
#define DD 2048
#define NOBJ 16
#define KK 3
#define NCLS 174
#define NCAT 321
#define NQ 4
#define QCAND 2048
#define NPART 16  /* per-wave partials per b: NQ blocks x 4 waves */

// ---------------- threefry2x32 (JAX-exact, 20 rounds) ----------------
__host__ __device__ __forceinline__ uint32_t rotl32(uint32_t x, int d) {
  return (x << d) | (x >> (32 - d));
}

__host__ __device__ __forceinline__ void threefry2x32(uint32_t k0, uint32_t k1,
                                                      uint32_t x0, uint32_t x1,
                                                      uint32_t& o0, uint32_t& o1) {
  uint32_t ks2 = k0 ^ k1 ^ 0x1BD11BDAu;
  x0 += k0; x1 += k1;
#define TFR(r) x0 += x1; x1 = rotl32(x1, r); x1 ^= x0;
#define R4A TFR(13) TFR(15) TFR(26) TFR(6)
#define R4B TFR(17) TFR(29) TFR(16) TFR(24)
  R4A x0 += k1;  x1 += ks2 + 1u;
  R4B x0 += ks2; x1 += k0 + 2u;
  R4A x0 += k0;  x1 += k1 + 3u;
  R4B x0 += k1;  x1 += ks2 + 4u;
  R4A x0 += ks2; x1 += k0 + 5u;
#undef R4A
#undef R4B
#undef TFR
  o0 = x0; o1 = x1;
}

__device__ __forceinline__ float bits_to_unit(uint32_t bits) {
  float f = __uint_as_float((bits >> 9) | 0x3f800000u);
  return f - 1.0f;
}

// ---- K1: pure sampler — (b, quarter) blocks, 4 waves each ----
// argmax(g + log w) == argmax(w / -log2(u)) (ln2 scale uniform -> argmax-safe).
// Cross-product compare avoids per-candidate division.
__global__ __launch_bounds__(256) void sample_kernel(
    const float* __restrict__ cooc, const int* __restrict__ obj_cat,
    const int* __restrict__ labels, uint32_t r1h, uint32_t r1l,
    unsigned long long* __restrict__ part, int* __restrict__ cnts) {
  const int gb = blockIdx.x;
  const int b = gb >> 2;
  const int q = gb & 3;
  const int tid = threadIdx.x;
  const int lane = tid & 63;
  const int wid = tid >> 6;

  __shared__ unsigned short jl[QCAND];  // per-wave 512-stripes, j-ascending
  __shared__ float wl[QCAND];

  const int lab = labels[b];
  const float* crow = cooc + (size_t)lab * NCAT;
  const int seg = wid << 9;
  const int jbase = (q << 11) + seg;

  // per-wave ordered compaction (ballot+popcount; no barriers needed)
  int cnt = 0;
#pragma unroll 1
  for (int c = 0; c < 8; ++c) {
    int j = jbase + (c << 6) + lane;
    int jb = j >> 4;
    float w = 0.0f;
    if (jb != b) w = crow[obj_cat[jb * NBOX + 2 + (j & 15)]];
    unsigned long long m = __ballot(w > 0.0f);
    if (w > 0.0f) {
      int rank = __popcll(m & ((1ull << lane) - 1ull));
      jl[seg + cnt + rank] = (unsigned short)j;
      wl[seg + cnt + rank] = w;
    }
    cnt += __popcll(m);
  }

  // 3-in-1 exponential races; t = -log2(u) via v_log_f32 (1 transcendental)
  const uint32_t cbase0 = ((uint32_t)b) << 13;  // k stride = 512*8192 = 1<<22
  const uint32_t kstep = 1u << 22;
  float bw0 = 0.f, bt0 = 1.f, bw1 = 0.f, bt1 = 1.f, bw2 = 0.f, bt2 = 1.f;
  int bj0 = 0, bj1 = 0, bj2 = 0;
#pragma unroll 1
  for (int p = lane; p < cnt; p += 64) {
    uint32_t j = jl[seg + p];
    float w = wl[seg + p];
    uint32_t cc = cbase0 + j;
    uint32_t x0, x1, y0, y1, z0, z1;
    threefry2x32(r1h, r1l, 0u, cc, x0, x1);
    threefry2x32(r1h, r1l, 0u, cc + kstep, y0, y1);
    threefry2x32(r1h, r1l, 0u, cc + 2u * kstep, z0, z1);
    // u is a multiple of 2^-23; clamp only u==0 (t=23: can never win, like ref)
    float t0 = -__log2f(fmaxf(bits_to_unit(x0 ^ x1), 1.1920929e-07f));
    float t1 = -__log2f(fmaxf(bits_to_unit(y0 ^ y1), 1.1920929e-07f));
    float t2 = -__log2f(fmaxf(bits_to_unit(z0 ^ z1), 1.1920929e-07f));
    if (w * bt0 > bw0 * t0) { bw0 = w; bt0 = t0; bj0 = (int)j; }  // strict >
    if (w * bt1 > bw1 * t1) { bw1 = w; bt1 = t1; bj1 = (int)j; }
    if (w * bt2 > bw2 * t2) { bw2 = w; bt2 = t2; bj2 = (int)j; }
  }
#pragma unroll
  for (int mm = 1; mm < 64; mm <<= 1) {
    float ow, ot; int oj;
    ow = __shfl_xor(bw0, mm, 64); ot = __shfl_xor(bt0, mm, 64); oj = __shfl_xor(bj0, mm, 64);
    { float l = ow * bt0, r = bw0 * ot;
      if (l > r || (l == r && oj < bj0)) { bw0 = ow; bt0 = ot; bj0 = oj; } }
    ow = __shfl_xor(bw1, mm, 64); ot = __shfl_xor(bt1, mm, 64); oj = __shfl_xor(bj1, mm, 64);
    { float l = ow * bt1, r = bw1 * ot;
      if (l > r || (l == r && oj < bj1)) { bw1 = ow; bt1 = ot; bj1 = oj; } }
    ow = __shfl_xor(bw2, mm, 64); ot = __shfl_xor(bt2, mm, 64); oj = __shfl_xor(bj2, mm, 64);
    { float l = ow * bt2, r = bw2 * ot;
      if (l > r || (l == r && oj < bj2)) { bw2 = ow; bt2 = ot; bj2 = oj; } }
  }
  if (lane == 0) {
    // packed partial: high = ratio bits (>=0, monotone), low = 8192-j (tie->min j)
    const int pw = q * 4 + wid;
    const size_t pb = (size_t)b * KK * NPART;
    part[pb + 0 * NPART + pw] =
        ((unsigned long long)__float_as_uint(bw0 / bt0) << 32) | (uint32_t)(8192 - bj0);
    part[pb + 1 * NPART + pw] =
        ((unsigned long long)__float_as_uint(bw1 / bt1) << 32) | (uint32_t)(8192 - bj1);
    part[pb + 2 * NPART + pw] =
        ((unsigned long long)__float_as_uint(bw2 / bt2) << 32) | (uint32_t)(8192 - bj2);
    cnts[b * NPART + pw] = cnt;
  }
}

// ---- K2: stream + mix — (b, D-half) blocks ----
__global__ __launch_bounds__(256) void stream_mix_kernel(
    const float* __restrict__ obj_fea, const int* __restrict__ obj_ind,
    const int* __restrict__ labels,
    const unsigned long long* __restrict__ part, const int* __restrict__ cnts,
    uint32_t r2h, uint32_t r2l, uint32_t r3bh, uint32_t r3bl,
    float* __restrict__ ori, float* __restrict__ mixf, float* __restrict__ mixl) {
  const int bx = blockIdx.x;
  const int b = bx >> 1;
  const int h = bx & 1;
  const int tid = threadIdx.x;
  const int off = (h << 8) + tid;  // float4 col in [0,512)

  __shared__ int s_sel[KK];
  __shared__ int s_slots[KK];
  __shared__ float s_lam;
  __shared__ int s_hc;

  // meta first: tiny loads issue before the stream
  if (tid < KK) {
    const int k = tid;
    const unsigned long long* pp = part + ((size_t)b * KK + k) * NPART;
    unsigned long long best = pp[0];
#pragma unroll
    for (int p = 1; p < NPART; ++p) {
      unsigned long long v = pp[p];
      if (v > best) best = v;
    }
    s_sel[k] = 8192 - (int)(best & 0xFFFFFFFFull);
    uint32_t s0, s1;
    threefry2x32(r3bh, r3bl, 0u, (uint32_t)(b * KK + k), s0, s1);
    s_slots[k] = (int)((s0 ^ s1) & 15u);
  } else if (tid == 3) {
    int tot = 0;
#pragma unroll
    for (int p = 0; p < NPART; ++p) tot += cnts[b * NPART + p];
    int any = 0;
#pragma unroll
    for (int o = 0; o < NOBJ; ++o) any |= (obj_ind[b * NBOX + 2 + o] != 0);
    s_hc = (tot > 0) && any;
  } else if (tid == 4) {
    uint32_t c0, c1;
    threefry2x32(r2h, r2l, 0u, (uint32_t)b, c0, c1);
    s_lam = bits_to_unit(c0 ^ c1);
  }

  // stream: sum 18 rows with a running accumulator (no spills)
  const float4* fea4 = (const float4*)obj_fea;
  const size_t rb = (size_t)b * NBOX * 512 + off;
  float4 v0 = fea4[rb];
  float4 v1 = fea4[rb + 512];
  float4 S = make_float4(v0.x + v1.x, v0.y + v1.y, v0.z + v1.z, v0.w + v1.w);
#pragma unroll
  for (int r = 2; r < NBOX; ++r) {
    float4 a = fea4[rb + (size_t)r * 512];
    S.x += a.x; S.y += a.y; S.z += a.z; S.w += a.w;
  }
  {
    const float is = 1.0f / 18.0f;
    ((float4*)ori)[(size_t)b * 512 + off] =
        make_float4(S.x * is, S.y * is, S.z * is, S.w * is);
  }
  float4 S16 = make_float4(S.x - v0.x - v1.x, S.y - v0.y - v1.y,
                           S.z - v0.z - v1.z, S.w - v0.w - v1.w);
  __syncthreads();

  const int hc = s_hc;
  const float l = s_lam, l1 = 1.0f - l;
  float4* mixf4 = (float4*)mixf;
  if (hc) {
#pragma unroll 1
    for (int k = 0; k < KK; ++k) {
      int s = s_sel[k];
      int bi = s >> 4, bo = s & 15, sl = s_slots[k];
      float4 a = fea4[((size_t)b * NBOX + 2 + sl) * 512 + off];
      float4 e = fea4[((size_t)bi * NBOX + 2 + bo) * 512 + off];
      float4 o;
      o.x = a.x * l + e.x * l1; o.y = a.y * l + e.y * l1;
      o.z = a.z * l + e.z * l1; o.w = a.w * l + e.w * l1;
      mixf4[((size_t)b * KK + k) * 512 + off] = o;
    }
  } else {
    const float is = 1.0f / 16.0f;
    float4 o = make_float4(S16.x * is, S16.y * is, S16.z * is, S16.w * is);
#pragma unroll
    for (int k = 0; k < KK; ++k) mixf4[((size_t)b * KK + k) * 512 + off] = o;
  }

  if (h == 0 && tid < NCLS) {
    int lb = labels[b];
#pragma unroll 1
    for (int k = 0; k < KK; ++k) {
      float val;
      if (hc) {
        int ls = labels[s_sel[k] >> 4];
        val = (tid == lb ? l : 0.0f) + (tid == ls ? l1 : 0.0f);
      } else {
        val = (tid == lb) ? 1.0f : 0.0f;
      }
      mixl[(size_t)(b * KK + k) * NCLS + tid] = val;
    }
  }
}

extern "C" void kernel_launch(void* const* d_in, const int* in_sizes, int n_in,
                              void* d_out, int out_size, void* d_ws, size_t ws_size,
                              hipStream_t stream) {
  (void)in_sizes; (void)n_in; (void)out_size; (void)ws_size;
  const float* obj_fea = (const float*)d_in[0];
  const float* cooc    = (const float*)d_in[1];
  const int* obj_ind   = (const int*)d_in[2];
  const int* obj_cat   = (const int*)d_in[3];
  const int* labels    = (const int*)d_in[4];

  float* out  = (float*)d_out;
  float* ori  = out;                              // 512*2048
  float* mixf = out + (size_t)BB * DD;            // 512*3*2048
  float* mixl = mixf + (size_t)BB * KK * DD;      // 512*3*174

  char* ws = (char*)d_ws;
  unsigned long long* part = (unsigned long long*)ws;      // 512*3*16*8 = 192 KB
  int* cnts = (int*)(ws + (size_t)BB * KK * NPART * 8);    // 512*16*4  =  32 KB

  // key(42) -> split 3 (partitionable/fold-like): r_i = threefry(key,(0,i))
  uint32_t r1h, r1l, r2h, r2l, r3h, r3l;
  threefry2x32(0u, 42u, 0u, 0u, r1h, r1l);
  threefry2x32(0u, 42u, 0u, 1u, r2h, r2l);
  threefry2x32(0u, 42u, 0u, 2u, r3h, r3l);
  // randint(r3,...) splits internally: k1,k2 = split(r3); lower_bits uses k2
  uint32_t r3bh, r3bl;
  threefry2x32(r3h, r3l, 0u, 1u, r3bh, r3bl);

  hipLaunchKernelGGL(sample_kernel, dim3(BB * NQ), dim3(256), 0, stream,
                     cooc, obj_cat, labels, r1h, r1l, part, cnts);
  hipLaunchKernelGGL(stream_mix_kernel, dim3(BB * 2), dim3(256), 0, stream,
                     obj_fea, obj_ind, labels, part, cnts,
                     r2h, r2l, r3bh, r3bl, ori, mixf, mixl);
}